// Round 7
// baseline (111.250 us; speedup 1.0000x reference)
//
#include <hip/hip_runtime.h>
#include <hip/hip_bf16.h>
#include <cstdint>

// Problem constants (reference: BATCH=4096, N_VIEWS=2, T=0.07, D=128 -> N=8192)
#define NROWS 8192
#define FDIM  128
#define HALF_N 4096

typedef short bf16x8 __attribute__((ext_vector_type(8)));   // 8 bf16 = 4 VGPRs
typedef float f32x4  __attribute__((ext_vector_type(4)));

// k1 = log2(e)/T so exp((s-1)/T) = exp2(k1*s - k1)
#define K1 (1.4426950408889634f / 0.07f)

#if __has_builtin(__builtin_amdgcn_exp2f)
#define EXP2(x) __builtin_amdgcn_exp2f(x)       // raw v_exp_f32
#else
#define EXP2(x) exp2f(x)
#endif

// Fragment-packed layout of the normalized bf16 matrix:
//   frag (rb, ks) at flat bf16x8 index (rb*4+ks)*64 + lane,
//   lane = quad*16 + (r&15) holds row r = rb*16+(lane&15), k = ks*32+quad*8..+8.
// One coalesced global_load_dwordx4 per fragment. 2 MB total.

// ---------------------------------------------------------------------------
// Kernel 1: L2-normalize rows (fp32, matching ref), write fragment-packed
// bf16. Also zero-inits esum_g and out[0].
// ---------------------------------------------------------------------------
__global__ void __launch_bounds__(256) normalize_kernel(const float* __restrict__ f,
                                                        short* __restrict__ packed,
                                                        float* __restrict__ esum_g,
                                                        float* __restrict__ out) {
    const int row  = blockIdx.x * 4 + (threadIdx.x >> 6);
    const int lane = threadIdx.x & 63;           // element k = 2*lane, 2*lane+1
    const float2 v = ((const float2*)(f + (size_t)row * FDIM))[lane];
    float ss = v.x * v.x + v.y * v.y;
    #pragma unroll
    for (int m = 1; m < 64; m <<= 1) ss += __shfl_xor(ss, m);
    const float scale = 1.0f / fmaxf(sqrtf(ss), 1e-12f);

    const int off = ((((row >> 4) * 4 + (lane >> 4)) * 64)
                     + ((lane >> 2) & 3) * 16 + (row & 15)) * 8 + 2 * (lane & 3);
    __hip_bfloat16 b0 = __float2bfloat16(v.x * scale);
    __hip_bfloat16 b1 = __float2bfloat16(v.y * scale);
    unsigned u = (unsigned)*(unsigned short*)&b0
               | ((unsigned)*(unsigned short*)&b1 << 16);
    *(unsigned*)(packed + off) = u;              // 4B-aligned (off is even)

    if (threadIdx.x < 4) esum_g[blockIdx.x * 4 + threadIdx.x] = 0.0f;
    if (blockIdx.x == 0 && threadIdx.x == 4) out[0] = 0.0f;
}

__device__ __forceinline__ float2 bf2_to_f2(unsigned u) {
    return make_float2(__uint_as_float(u << 16),
                       __uint_as_float(u & 0xffff0000u));
}

// ---------------------------------------------------------------------------
// Kernel 2: SYMMETRIC fused sim+exp+rowsum — NO col-sum atomics this time.
// 128 row-strips of 64 rows. Strip i, bands d = 0..64 (tile (i, (i+d)&127)):
//   d=1..63 : row-sums -> esum[strip i] (register ep, atomic commit at end);
//             col-sums -> PLAIN STORE to col_scratch[d-1][i][64] (each slot
//             written exactly once; folded later by reduce_kernel).
//   d=0, 64 : row-sums only.
// cb unit = (d, fc): 16 cols x 64 rows x K=128 = 16 MFMA. 260 cbs/strip.
// 24 waves/strip (c = 0..23, p = c + 24k) -> 768 blocks = 3 blocks/CU
// (round-5 occupancy was GRID-limited at 2). Register ping-pong prefetch.
// Block's 4 waves have adjacent c -> same-step B-tiles alias in L1.
// Blocks 768..799: pos_i = <f_i, f_(i^4096)>, diag_i = exp((<f_i,f_i>-1)/T).
// ---------------------------------------------------------------------------
__global__ void __launch_bounds__(256, 3) sim_kernel(const short* __restrict__ pk,
                                                     float* __restrict__ esum_g,
                                                     float* __restrict__ pos_g,
                                                     float* __restrict__ diag_g,
                                                     float* __restrict__ colsc) {
    if (blockIdx.x >= 768) {
        // ---- pos/diag path: one thread per row ----
        const int i  = (blockIdx.x - 768) * 256 + threadIdx.x;
        const int ip = i ^ HALF_N;
        const uint4* P = (const uint4*)pk;
        float dot = 0.f, self = 0.f;
        #pragma unroll
        for (int cc = 0; cc < 16; cc++) {        // cc = ks*4 + quad
            const uint4 a = P[((i  >> 4) * 4 + (cc >> 2)) * 64 + (cc & 3) * 16 + (i  & 15)];
            const uint4 b = P[((ip >> 4) * 4 + (cc >> 2)) * 64 + (cc & 3) * 16 + (ip & 15)];
            const unsigned au[4] = {a.x, a.y, a.z, a.w};
            const unsigned bu[4] = {b.x, b.y, b.z, b.w};
            #pragma unroll
            for (int q = 0; q < 4; q++) {
                const float2 av = bf2_to_f2(au[q]);
                const float2 bv = bf2_to_f2(bu[q]);
                dot  = __builtin_fmaf(av.x, bv.x, __builtin_fmaf(av.y, bv.y, dot));
                self = __builtin_fmaf(av.x, av.x, __builtin_fmaf(av.y, av.y, self));
            }
        }
        pos_g[i]  = dot;
        diag_g[i] = EXP2(__builtin_fmaf(self, K1, -K1));
        return;
    }

    const int tid   = threadIdx.x;
    const int w     = tid >> 6;
    const int lane  = tid & 63;
    const int quad  = lane >> 4;
    const int l16   = lane & 15;
    const int strip = blockIdx.x / 6;            // 0..127
    const int c     = (blockIdx.x % 6) * 4 + w;  // 0..23
    const bf16x8* P = (const bf16x8*)pk;

    // A fragments for this wave's 64 rows (strip), parked: a_reg[ks][fr]
    bf16x8 a_reg[4][4];
    #pragma unroll
    for (int fr = 0; fr < 4; fr++)
        #pragma unroll
        for (int ks = 0; ks < 4; ks++)
            a_reg[ks][fr] = P[((strip * 4 + fr) * 4 + ks) * 64 + lane];

    float ep[4][4];                              // [fr][r] row partials
    #pragma unroll
    for (int a = 0; a < 4; a++)
        #pragma unroll
        for (int b = 0; b < 4; b++) ep[a][b] = 0.0f;

    // cb p (0..259) -> flat bf16x8 operand base (ks advances by 64)
    auto cb_base = [&](int p) {
        const int d = p >> 2, fc = p & 3;
        const int js = (strip + d) & 127;
        return ((js * 4 + fc) * 4) * 64 + lane;
    };

    bf16x8 bb[2][4];
    {
        const int b0 = cb_base(c);               // c < 24, always valid
        #pragma unroll
        for (int ks = 0; ks < 4; ks++) bb[0][ks] = P[b0 + ks * 64];
    }

    #pragma unroll
    for (int k = 0; k < 11; k++) {               // p = c + 24k, max 10*24+23=263
        if (k < 10) {                            // prefetch next (clamp to c)
            const int pn = c + 24 * (k + 1);
            const int bn = cb_base(pn < 260 ? pn : c);
            #pragma unroll
            for (int ks = 0; ks < 4; ks++)
                bb[(k + 1) & 1][ks] = P[bn + ks * 64];
        }
        const int p = c + 24 * k;
        if (p < 260) {                           // wave-uniform guard
            const int d  = p >> 2, fc = p & 3;
            const int js = (strip + d) & 127;

            f32x4 acc[4];
            #pragma unroll
            for (int fr = 0; fr < 4; fr++) acc[fr] = (f32x4){0.f, 0.f, 0.f, 0.f};
            #pragma unroll
            for (int ks = 0; ks < 4; ks++)
                #pragma unroll
                for (int fr = 0; fr < 4; fr++)
                    acc[fr] = __builtin_amdgcn_mfma_f32_16x16x32_bf16(
                                  a_reg[ks][fr], bb[k & 1][ks], acc[fr], 0, 0, 0);

            // e = exp((s-1)/T); row partials always; col-sums for d=1..63
            float cs = 0.0f;
            #pragma unroll
            for (int fr = 0; fr < 4; fr++)
                #pragma unroll
                for (int r = 0; r < 4; r++) {
                    const float e = EXP2(__builtin_fmaf(acc[fr][r], K1, -K1));
                    ep[fr][r] += e;
                    cs += e;
                }
            if (d != 0 && d != 64) {             // wave-uniform branch
                cs += __shfl_xor(cs, 16);        // sum over quad bits ->
                cs += __shfl_xor(cs, 32);        // full 64-row column sum
                if (lane < 16)                   // one 64B quarter-wave store
                    colsc[((d - 1) * 128 + strip) * 64 + fc * 16 + lane] = cs;
            }
        }
    }

    // reduce row partials across the 16 column-lanes, commit once per wave
    #pragma unroll
    for (int fr = 0; fr < 4; fr++)
        #pragma unroll
        for (int r = 0; r < 4; r++) {
            float v = ep[fr][r];
            #pragma unroll
            for (int m = 1; m < 16; m <<= 1) v += __shfl_xor(v, m);
            if (l16 == 0)
                atomicAdd(&esum_g[strip * 64 + fr * 16 + quad * 4 + r], v);
        }
}

// ---------------------------------------------------------------------------
// Kernel 3: fold col_scratch into esum, compute loss, mean into out[0].
// One thread per row; consecutive lanes read consecutive scratch cols
// (coalesced 256B per (d, warp-quarter)). 32 block-atomicAdds total.
// ---------------------------------------------------------------------------
__global__ void __launch_bounds__(256) reduce_kernel(const float* __restrict__ esum_g,
                                                     const float* __restrict__ pos_g,
                                                     const float* __restrict__ diag_g,
                                                     const float* __restrict__ colsc,
                                                     float* __restrict__ out) {
    const int j   = blockIdx.x * 256 + threadIdx.x;   // global row
    const int js  = j >> 6, c64 = j & 63;
    float cs = 0.0f;
    #pragma unroll 7
    for (int d = 1; d <= 63; d++)
        cs += colsc[((d - 1) * 128 + ((js - d) & 127)) * 64 + c64];
    const float invT = 1.0f / 0.07f;
    float loss = logf(esum_g[j] + cs - diag_g[j]) + invT - pos_g[j] * invT;
    #pragma unroll
    for (int m = 1; m < 64; m <<= 1) loss += __shfl_xor(loss, m);
    __shared__ float wsm[4];
    if ((threadIdx.x & 63) == 0) wsm[threadIdx.x >> 6] = loss;
    __syncthreads();
    if (threadIdx.x == 0)
        atomicAdd(out, (wsm[0] + wsm[1] + wsm[2] + wsm[3]) * (1.0f / (float)NROWS));
}

// ---------------------------------------------------------------------------
extern "C" void kernel_launch(void* const* d_in, const int* in_sizes, int n_in,
                              void* d_out, int out_size, void* d_ws, size_t ws_size,
                              hipStream_t stream) {
    const float* features = (const float*)d_in[0];
    float* out = (float*)d_out;

    char* ws = (char*)d_ws;
    short* packed = (short*)ws;                                          // 2 MB
    float* esum_g = (float*)(ws + 2097152);                              // 32 KB
    float* pos_g  = (float*)(ws + 2097152 + 32768);                      // 32 KB
    float* diag_g = (float*)(ws + 2097152 + 65536);                      // 32 KB
    float* colsc  = (float*)(ws + 2097152 + 98304);                      // ~2 MB

    normalize_kernel<<<NROWS / 4, 256, 0, stream>>>(features, packed, esum_g, out);

    sim_kernel<<<768 + NROWS / 256, 256, 0, stream>>>(packed, esum_g, pos_g,
                                                      diag_g, colsc);

    reduce_kernel<<<NROWS / 256, 256, 0, stream>>>(esum_g, pos_g, diag_g, colsc, out);
}

// Round 8
// 88.862 us; speedup vs baseline: 1.2519x; 1.2519x over previous
//
#include <hip/hip_runtime.h>
#include <hip/hip_bf16.h>
#include <cstdint>

// Problem constants (reference: BATCH=4096, N_VIEWS=2, T=0.07, D=128 -> N=8192)
#define NROWS 8192
#define FDIM  128
#define HALF_N 4096

typedef short bf16x8 __attribute__((ext_vector_type(8)));   // 8 bf16 = 4 VGPRs
typedef float f32x4  __attribute__((ext_vector_type(4)));

// k1 = log2(e)/T so exp((s-1)/T) = exp2(k1*s - k1)
#define K1 (1.4426950408889634f / 0.07f)

#if __has_builtin(__builtin_amdgcn_exp2f)
#define EXP2(x) __builtin_amdgcn_exp2f(x)       // raw v_exp_f32
#else
#define EXP2(x) exp2f(x)
#endif

// Fragment-packed layout of the normalized bf16 matrix:
//   frag (rb, ks) at flat bf16x8 index (rb*4+ks)*64 + lane,
//   lane = quad*16 + (r&15) holds row r = rb*16+(lane&15), k = ks*32+quad*8..+8.
// One coalesced global_load_dwordx4 per fragment. 2 MB total.

// ---------------------------------------------------------------------------
// Kernel 1: L2-normalize rows (fp32, matching ref), write fragment-packed
// bf16. Also zero-inits esum_g.
// ---------------------------------------------------------------------------
__global__ void __launch_bounds__(256) normalize_kernel(const float* __restrict__ f,
                                                        short* __restrict__ packed,
                                                        float* __restrict__ esum_g) {
    const int row  = blockIdx.x * 4 + (threadIdx.x >> 6);
    const int lane = threadIdx.x & 63;           // element k = 2*lane, 2*lane+1
    const float2 v = ((const float2*)(f + (size_t)row * FDIM))[lane];
    float ss = v.x * v.x + v.y * v.y;
    #pragma unroll
    for (int m = 1; m < 64; m <<= 1) ss += __shfl_xor(ss, m);
    const float scale = 1.0f / fmaxf(sqrtf(ss), 1e-12f);

    const int off = ((((row >> 4) * 4 + (lane >> 4)) * 64)
                     + ((lane >> 2) & 3) * 16 + (row & 15)) * 8 + 2 * (lane & 3);
    __hip_bfloat16 b0 = __float2bfloat16(v.x * scale);
    __hip_bfloat16 b1 = __float2bfloat16(v.y * scale);
    unsigned u = (unsigned)*(unsigned short*)&b0
               | ((unsigned)*(unsigned short*)&b1 << 16);
    *(unsigned*)(packed + off) = u;              // 4B-aligned (off is even)

    if (threadIdx.x < 4) esum_g[blockIdx.x * 4 + threadIdx.x] = 0.0f;
}

__device__ __forceinline__ float2 bf2_to_f2(unsigned u) {
    return make_float2(__uint_as_float(u << 16),
                       __uint_as_float(u & 0xffff0000u));
}

// ---------------------------------------------------------------------------
// Kernel 2: full-matrix fused sim+exp+rowsum (round-5 memory behavior, 2x TLP).
// 4096 compute waves: wave = (strip of 32 rows, j of 512 cols). Block = 4
// waves sharing j over strips sg*4..+3 (B-stream aliases in L1; A contiguous).
// Grid 1024 -> 4 blocks/CU, __launch_bounds__(256,4): 4 waves/SIMD of latency
// hiding (round 5 had 2 — its stall source). A parked in 32 VGPR; per cb
// (16 cols): 4 B-frag loads + 8 MFMA + 8 exp2 per lane; unroll-8 lets the
// compiler hoist loads across iterations (~38 spare VGPRs).
// esum includes the diagonal term (subtracted in final via diag_g).
// Blocks 1024..1055: pos_i = <f_i, f_(i^4096)>, diag_i = exp((<f_i,f_i>-1)/T).
// ---------------------------------------------------------------------------
__global__ void __launch_bounds__(256, 4) sim_kernel(const short* __restrict__ pk,
                                                     float* __restrict__ esum_g,
                                                     float* __restrict__ pos_g,
                                                     float* __restrict__ diag_g) {
    if (blockIdx.x >= 1024) {
        // ---- pos/diag path: one thread per row ----
        const int i  = (blockIdx.x - 1024) * 256 + threadIdx.x;
        const int ip = i ^ HALF_N;
        const uint4* P = (const uint4*)pk;
        float dot = 0.f, self = 0.f;
        #pragma unroll
        for (int cc = 0; cc < 16; cc++) {        // cc = ks*4 + quad
            const uint4 a = P[((i  >> 4) * 4 + (cc >> 2)) * 64 + (cc & 3) * 16 + (i  & 15)];
            const uint4 b = P[((ip >> 4) * 4 + (cc >> 2)) * 64 + (cc & 3) * 16 + (ip & 15)];
            const unsigned au[4] = {a.x, a.y, a.z, a.w};
            const unsigned bu[4] = {b.x, b.y, b.z, b.w};
            #pragma unroll
            for (int q = 0; q < 4; q++) {
                const float2 av = bf2_to_f2(au[q]);
                const float2 bv = bf2_to_f2(bu[q]);
                dot  = __builtin_fmaf(av.x, bv.x, __builtin_fmaf(av.y, bv.y, dot));
                self = __builtin_fmaf(av.x, av.x, __builtin_fmaf(av.y, av.y, self));
            }
        }
        pos_g[i]  = dot;
        diag_g[i] = EXP2(__builtin_fmaf(self, K1, -K1));
        return;
    }

    const int tid   = threadIdx.x;
    const int w     = tid >> 6;
    const int lane  = tid & 63;
    const int quad  = lane >> 4;
    const int l16   = lane & 15;
    const int j     = blockIdx.x & 15;           // col group (512 cols), SHARED
    const int strip = (blockIdx.x >> 4) * 4 + w; // 0..255: rows strip*32..+32
    const bf16x8* P = (const bf16x8*)pk;

    // A fragments for this wave's 32 rows, parked: a_reg[ks][fr] (32 VGPR)
    bf16x8 a_reg[4][2];
    #pragma unroll
    for (int fr = 0; fr < 2; fr++)
        #pragma unroll
        for (int ks = 0; ks < 4; ks++)
            a_reg[ks][fr] = P[(((strip * 2 + fr) * 4) + ks) * 64 + lane];

    float ep[2][4];                              // [fr][r] row partials
    #pragma unroll
    for (int a = 0; a < 2; a++)
        #pragma unroll
        for (int b = 0; b < 4; b++) ep[a][b] = 0.0f;

    const int cb0 = j * 32;                      // 32 col-blocks of 16

    #pragma unroll 8
    for (int cb = 0; cb < 32; cb++) {
        bf16x8 b[4];
        #pragma unroll
        for (int ks = 0; ks < 4; ks++)
            b[ks] = P[((cb0 + cb) * 4 + ks) * 64 + lane];

        f32x4 acc[2];
        #pragma unroll
        for (int fr = 0; fr < 2; fr++) acc[fr] = (f32x4){0.f, 0.f, 0.f, 0.f};
        #pragma unroll
        for (int ks = 0; ks < 4; ks++)
            #pragma unroll
            for (int fr = 0; fr < 2; fr++)
                acc[fr] = __builtin_amdgcn_mfma_f32_16x16x32_bf16(
                              a_reg[ks][fr], b[ks], acc[fr], 0, 0, 0);

        #pragma unroll
        for (int fr = 0; fr < 2; fr++)
            #pragma unroll
            for (int r = 0; r < 4; r++)
                ep[fr][r] += EXP2(__builtin_fmaf(acc[fr][r], K1, -K1));
    }

    // reduce row partials across the 16 column-lanes, commit once per wave
    #pragma unroll
    for (int fr = 0; fr < 2; fr++)
        #pragma unroll
        for (int r = 0; r < 4; r++) {
            float v = ep[fr][r];
            #pragma unroll
            for (int m = 1; m < 16; m <<= 1) v += __shfl_xor(v, m);
            if (l16 == 0)
                atomicAdd(&esum_g[strip * 32 + fr * 16 + quad * 4 + r], v);
        }
}

// ---------------------------------------------------------------------------
// Kernel 3: loss_i = ln(esum_i - diag_i) + 1/T - pos_i/T ; out = mean(loss).
// ---------------------------------------------------------------------------
__global__ void __launch_bounds__(256) final_kernel(const float* __restrict__ esum_g,
                                                    const float* __restrict__ pos_g,
                                                    const float* __restrict__ diag_g,
                                                    float* __restrict__ out) {
    const int tid = threadIdx.x;
    const float invT = 1.0f / 0.07f;
    float acc = 0.0f;
    for (int i = tid; i < NROWS; i += 256)
        acc += logf(esum_g[i] - diag_g[i]) + invT - pos_g[i] * invT;
    #pragma unroll
    for (int m = 1; m < 64; m <<= 1) acc += __shfl_xor(acc, m);
    __shared__ float ws[4];
    if ((tid & 63) == 0) ws[tid >> 6] = acc;
    __syncthreads();
    if (tid == 0) out[0] = (ws[0] + ws[1] + ws[2] + ws[3]) * (1.0f / (float)NROWS);
}

// ---------------------------------------------------------------------------
extern "C" void kernel_launch(void* const* d_in, const int* in_sizes, int n_in,
                              void* d_out, int out_size, void* d_ws, size_t ws_size,
                              hipStream_t stream) {
    const float* features = (const float*)d_in[0];
    float* out = (float*)d_out;

    char* ws = (char*)d_ws;
    short* packed = (short*)ws;                                          // 2 MB
    float* esum_g = (float*)(ws + 2097152);                              // 32 KB
    float* pos_g  = (float*)(ws + 2097152 + 32768);                      // 32 KB
    float* diag_g = (float*)(ws + 2097152 + 65536);                      // 32 KB

    normalize_kernel<<<NROWS / 4, 256, 0, stream>>>(features, packed, esum_g);

    sim_kernel<<<1024 + NROWS / 256, 256, 0, stream>>>(packed, esum_g, pos_g, diag_g);

    final_kernel<<<1, 256, 0, stream>>>(esum_g, pos_g, diag_g, out);
}